// Round 9
// baseline (139.845 us; speedup 1.0000x reference)
//
#include <hip/hip_runtime.h>

// vol [B=2, 192,192,192, C=1] fp32, affine [B,3,4] fp32,
// out [B,192,192,192,1] fp32.
#define DIM   192
#define PLANE (DIM * DIM)
#define NB    2

// Output brick per 256-thread block; LDS staging tile with COMPILE-TIME strides.
#define TW 32
#define TH 8
#define TD 8
#define SW 40            // staged cols capacity
#define SH 12            // staged rows capacity
#define SD 12            // staged planes capacity
#define RS 42            // row stride (floats): 42%32=10 -> <=2-way bank alias (free)
#define PS (RS * SH)     // plane stride = 504
#define LDSF (PS * SD)   // 6048 floats = 24.2 KB -> 6 blocks/CU
#define MARG 0.001f      // bbox guard vs fp reassociation between tile/voxel paths

typedef float f2 __attribute__((ext_vector_type(2), aligned(4)));

__device__ __forceinline__ float med3(float x, float lo, float hi) {
    return __builtin_amdgcn_fmed3f(x, lo, hi);
}

__global__ __launch_bounds__(256) void
SpatialTransformer_warp_kernel(const float* __restrict__ vol,
                               const float* __restrict__ affine,
                               float* __restrict__ out) {
    __shared__ float lds[LDSF];

    const int tid = threadIdx.x;
    const int wl  = tid & 31;             // 0..31 within tile
    const int hl  = tid >> 5;             // 0..7
    const int w0  = blockIdx.x * TW;
    const int h0  = blockIdx.y * TH;
    const int z   = blockIdx.z;           // (d-tile | b)
    const int b   = (z >= DIM / TD) ? 1 : 0;
    const int d0  = (z - b * (DIM / TD)) * TD;

    const float* __restrict__ A = affine + b * 12;
    const float a00 = A[0], a01 = A[1], a02 = A[2],  a03 = A[3];
    const float a10 = A[4], a11 = A[5], a12 = A[6],  a13 = A[7];
    const float a20 = A[8], a21 = A[9], a22 = A[10], a23 = A[11];

    const float center = (DIM - 1) * 0.5f;   // 95.5
    const float maxl   = (float)(DIM - 1);   // 191.0
    const float maxi0  = (float)(DIM - 2);   // 190.0

    // ---- bbox of transformed brick (min/max over 8 corners; linear map) ----
    float lmn0, lmx0, lmn1, lmx1, lmn2, lmx2;
    {
#pragma unroll
        for (int c = 0; c < 8; ++c) {
            const float fd = (float)(d0 + (((c >> 2) & 1) ? TD - 1 : 0)) - center;
            const float fh = (float)(h0 + (((c >> 1) & 1) ? TH - 1 : 0)) - center;
            const float fw = (float)(w0 + ((c & 1) ? TW - 1 : 0)) - center;
            const float m0 = a00 * fd + a01 * fh + a02 * fw + a03 + center;
            const float m1 = a10 * fd + a11 * fh + a12 * fw + a13 + center;
            const float m2 = a20 * fd + a21 * fh + a22 * fw + a23 + center;
            if (c == 0) {
                lmn0 = lmx0 = m0; lmn1 = lmx1 = m1; lmn2 = lmx2 = m2;
            } else {
                lmn0 = fminf(lmn0, m0); lmx0 = fmaxf(lmx0, m0);
                lmn1 = fminf(lmn1, m1); lmx1 = fmaxf(lmx1, m1);
                lmn2 = fminf(lmn2, m2); lmx2 = fmaxf(lmx2, m2);
            }
        }
    }
    // i0(l) = min(floor(med3(l,0,191)),190) is monotone; pad by MARG for safety.
    const float flo_d = fminf(floorf(med3(lmn0 - MARG, 0.0f, maxl)), maxi0);
    const float flo_h = fminf(floorf(med3(lmn1 - MARG, 0.0f, maxl)), maxi0);
    const float flo_w = fminf(floorf(med3(lmn2 - MARG, 0.0f, maxl)), maxi0);
    const int lo_d = (int)flo_d, lo_h = (int)flo_h, lo_w = (int)flo_w;
    const int dd = (int)fminf(floorf(med3(lmx0 + MARG, 0.0f, maxl)), maxi0) + 2 - lo_d;
    const int dh = (int)fminf(floorf(med3(lmx1 + MARG, 0.0f, maxl)), maxi0) + 2 - lo_h;
    const int dw = (int)fminf(floorf(med3(lmx2 + MARG, 0.0f, maxl)), maxi0) + 2 - lo_w;

    // Per-thread constants (h, w fixed; d varies in the voxel loop)
    const float ch = (float)(h0 + hl) - center;
    const float cw = (float)(w0 + wl) - center;
    const float K0 = a01 * ch + a02 * cw + a03 + center;
    const float K1 = a11 * ch + a12 * cw + a13 + center;
    const float K2 = a21 * ch + a22 * cw + a23 + center;

    const float* __restrict__ vb = vol + (size_t)b * DIM * PLANE;
    float* __restrict__ ob = out + ((size_t)b * DIM + d0) * PLANE
                                 + (size_t)(h0 + hl) * DIM + (w0 + wl);

    const bool fits = (dd <= SD) && (dh <= SH) && (dw <= SW);  // block-uniform

    if (fits) {
        // ---- stage bbox -> LDS: all 256 lanes, compile-time strides ----
        const int wlim = (DIM - 1) - lo_w;     // col clamp (stays in-bounds)
        const int rowelems = dh * SW;          // <= 480 -> 2 iterations
        for (int zz = 0; zz < dd; ++zz) {
            const float* __restrict__ src = vb + (lo_d + zz) * PLANE + lo_h * DIM + lo_w;
            float* __restrict__ dst = lds + zz * PS;
#pragma unroll
            for (int it = 0; it < 2; ++it) {
                const int idx = it * 256 + tid;
                if (idx < rowelems) {
                    const int y = idx / SW;            // const-div -> magic mul
                    const int c = idx - y * SW;
                    dst[y * RS + c] = src[y * DIM + min(c, wlim)];
                }
            }
        }
        __syncthreads();

#pragma unroll
        for (int dz = 0; dz < TD; ++dz) {
            const float cd = (float)(d0 + dz) - center;
            const float ld = a00 * cd + K0;
            const float lh = a10 * cd + K1;
            const float lw = a20 * cd + K2;

            const float td = med3(ld, 0.0f, maxl);
            const float th = med3(lh, 0.0f, maxl);
            const float tw = med3(lw, 0.0f, maxl);
            const float fd = fminf(floorf(td), maxi0);
            const float fh = fminf(floorf(th), maxi0);
            const float fw = fminf(floorf(tw), maxi0);
            const float w0d = fd + 1.0f - td;
            const float w0h = fh + 1.0f - th;
            const float w0w = fw + 1.0f - tw;

            // local flat index, exact in fp32 (integer-valued, < 2^24)
            const int idx = (int)__builtin_fmaf(fd - flo_d, (float)PS,
                              __builtin_fmaf(fh - flo_h, (float)RS, fw - flo_w));
            const float* __restrict__ p = lds + idx;
            const float v000 = p[0],       v001 = p[1];
            const float v010 = p[RS],      v011 = p[RS + 1];
            const float v100 = p[PS],      v101 = p[PS + 1];
            const float v110 = p[PS + RS], v111 = p[PS + RS + 1];

            const float w1w = 1.0f - w0w, w1h = 1.0f - w0h, w1d = 1.0f - w0d;
            const float x00 = v000 * w0w + v001 * w1w;
            const float x01 = v010 * w0w + v011 * w1w;
            const float x10 = v100 * w0w + v101 * w1w;
            const float x11 = v110 * w0w + v111 * w1w;
            const float y0 = x00 * w0h + x01 * w1h;
            const float y1 = x10 * w0h + x11 * w1h;
            __builtin_nontemporal_store(y0 * w0d + y1 * w1d, ob + dz * PLANE);
        }
    } else {
        // ---- fallback: direct global gather (identical per-voxel semantics) ----
#pragma unroll
        for (int dz = 0; dz < TD; ++dz) {
            const float cd = (float)(d0 + dz) - center;
            const float ld = a00 * cd + K0;
            const float lh = a10 * cd + K1;
            const float lw = a20 * cd + K2;

            const float td = med3(ld, 0.0f, maxl);
            const float th = med3(lh, 0.0f, maxl);
            const float tw = med3(lw, 0.0f, maxl);
            const float fd = fminf(floorf(td), maxi0);
            const float fh = fminf(floorf(th), maxi0);
            const float fw = fminf(floorf(tw), maxi0);
            const float w0d = fd + 1.0f - td;
            const float w0h = fh + 1.0f - th;
            const float w0w = fw + 1.0f - tw;

            const int idx = (int)__builtin_fmaf(fd, (float)PLANE,
                              __builtin_fmaf(fh, (float)DIM, fw));
            const f2 r00 = *(const f2*)(vb + idx);
            const f2 r01 = *(const f2*)(vb + idx + DIM);
            const f2 r10 = *(const f2*)(vb + idx + PLANE);
            const f2 r11 = *(const f2*)(vb + idx + PLANE + DIM);

            const float w1w = 1.0f - w0w, w1h = 1.0f - w0h, w1d = 1.0f - w0d;
            const float x00 = r00.x * w0w + r00.y * w1w;
            const float x01 = r01.x * w0w + r01.y * w1w;
            const float x10 = r10.x * w0w + r10.y * w1w;
            const float x11 = r11.x * w0w + r11.y * w1w;
            const float y0 = x00 * w0h + x01 * w1h;
            const float y1 = x10 * w0h + x11 * w1h;
            __builtin_nontemporal_store(y0 * w0d + y1 * w1d, ob + dz * PLANE);
        }
    }
}

extern "C" void kernel_launch(void* const* d_in, const int* in_sizes, int n_in,
                              void* d_out, int out_size, void* d_ws, size_t ws_size,
                              hipStream_t stream) {
    const float* vol    = (const float*)d_in[0];
    const float* affine = (const float*)d_in[1];
    float* out = (float*)d_out;

    dim3 grid(DIM / TW, DIM / TH, NB * (DIM / TD));  // (w-tile, h-tile, d-tile|b)
    dim3 block(256);
    SpatialTransformer_warp_kernel<<<grid, block, 0, stream>>>(vol, affine, out);
}

// Round 10
// 136.396 us; speedup vs baseline: 1.0253x; 1.0253x over previous
//
#include <hip/hip_runtime.h>

// vol [B=2, 192,192,192, C=1] fp32, affine [B,3,4] fp32,
// out [B,192,192,192,1] fp32.
#define DIM   192
#define PLANE (DIM * DIM)
#define NB    2
#define DPT   4   // d-voxels per thread (plane reuse in-thread)
#define BH    4   // h rows per block (row reuse in L1 across waves)

// Grid decomposition (1-D launch, XCD-swizzled):
#define GX   (DIM / 64)          // 3   w-tiles
#define GY   (DIM / BH)          // 48  h-tiles
#define GZ   (NB * (DIM / DPT))  // 96  (d-quad | b) tiles
#define NXCD 8
#define ZL   (GZ / NXCD)         // 12  z-tiles per XCD slab

typedef float f2 __attribute__((ext_vector_type(2), aligned(4)));

__global__ __launch_bounds__(256) void
SpatialTransformer_warp_kernel(const float* __restrict__ vol,
                               const float* __restrict__ affine,
                               float* __restrict__ out) {
    // ---- XCD-aware swizzle: consecutive block ids round-robin across XCDs.
    // Give each XCD a contiguous z-slab so its private 4 MiB L2 holds the
    // active gather footprint (~2 z-tiles ~ 1.5 MB) instead of ~10 MB.
    const int id  = blockIdx.x;
    const int xcd = id & (NXCD - 1);
    const int j   = id >> 3;           // 0 .. GX*GY*ZL-1 within this XCD
    const int bx  = j % GX;
    const int t   = j / GX;
    const int by  = t % GY;
    const int zl  = t / GY;            // 0..ZL-1
    const int z   = xcd * ZL + zl;     // (d-quad | b) tile

    const int tid = threadIdx.x;
    const int w   = (bx << 6) + (tid & 63);   // 64-lane wave along w
    const int h   = by * BH + (tid >> 6);     // 4 h rows per block
    const int b   = (z >= DIM / DPT) ? 1 : 0;
    const int d0  = (z - b * (DIM / DPT)) * DPT;

    const float* __restrict__ A = affine + b * 12;
    const float a00 = A[0], a01 = A[1], a02 = A[2],  a03 = A[3];
    const float a10 = A[4], a11 = A[5], a12 = A[6],  a13 = A[7];
    const float a20 = A[8], a21 = A[9], a22 = A[10], a23 = A[11];

    const float center = (DIM - 1) * 0.5f;   // 95.5
    const float maxl   = (float)(DIM - 1);   // 191.0
    const float maxi0  = (float)(DIM - 2);   // 190.0
    const float fplane = (float)PLANE;       // 36864.0
    const float fdim   = (float)DIM;         // 192.0

    const float ch = (float)h - center;
    const float cw = (float)w - center;

    // Partial sums independent of d
    const float pd = a01 * ch + a02 * cw + a03 + center;
    const float ph = a11 * ch + a12 * cw + a13 + center;
    const float pw = a21 * ch + a22 * cw + a23 + center;

    const float* __restrict__ vb = vol + (size_t)b * DIM * PLANE;
    float* __restrict__ ob = out + ((size_t)b * DIM + d0) * PLANE
                                 + (size_t)h * DIM + w;

    f2 r00[DPT], r01[DPT], r10[DPT], r11[DPT];
    float w0d_[DPT], w0h_[DPT], w0w_[DPT];

#pragma unroll
    for (int k = 0; k < DPT; ++k) {
        const float cd = (float)(d0 + k) - center;
        const float ld = a00 * cd + pd;
        const float lh = a10 * cd + ph;
        const float lw = a20 * cd + pw;

        // i0 = min(floor(clamp(l,0,191)),190); i1 = i0+1; w0 = i0+1 - clamp(l).
        // Identical to reference semantics (right-clamped corner has zero weight).
        const float td = __builtin_amdgcn_fmed3f(ld, 0.0f, maxl);
        const float th = __builtin_amdgcn_fmed3f(lh, 0.0f, maxl);
        const float tw = __builtin_amdgcn_fmed3f(lw, 0.0f, maxl);

        const float fd = fminf(floorf(td), maxi0);
        const float fh = fminf(floorf(th), maxi0);
        const float fw = fminf(floorf(tw), maxi0);

        w0d_[k] = fd + 1.0f - td;
        w0h_[k] = fh + 1.0f - th;
        w0w_[k] = fw + 1.0f - tw;

        // Flat index in float: all values integer-valued and < 2^24 -> exact.
        const int idx = (int)__builtin_fmaf(fd, fplane, __builtin_fmaf(fh, fdim, fw));
        const float* p = vb + idx;

        r00[k] = *(const f2*)(p);                   // (d0, h0, w0..w0+1)
        r01[k] = *(const f2*)(p + DIM);             // (d0, h0+1)
        r10[k] = *(const f2*)(p + PLANE);           // (d0+1, h0) — next k's (d0, h0)
        r11[k] = *(const f2*)(p + PLANE + DIM);     // (d0+1, h0+1)
    }

#pragma unroll
    for (int k = 0; k < DPT; ++k) {
        const float w0w = w0w_[k], w1w = 1.0f - w0w;
        const float w0h = w0h_[k], w1h = 1.0f - w0h;
        const float w0d = w0d_[k], w1d = 1.0f - w0d;

        const float x00 = r00[k].x * w0w + r00[k].y * w1w;
        const float x01 = r01[k].x * w0w + r01[k].y * w1w;
        const float x10 = r10[k].x * w0w + r10[k].y * w1w;
        const float x11 = r11[k].x * w0w + r11[k].y * w1w;

        const float y0 = x00 * w0h + x01 * w1h;
        const float y1 = x10 * w0h + x11 * w1h;

        __builtin_nontemporal_store(y0 * w0d + y1 * w1d, ob + k * PLANE);
    }
}

extern "C" void kernel_launch(void* const* d_in, const int* in_sizes, int n_in,
                              void* d_out, int out_size, void* d_ws, size_t ws_size,
                              hipStream_t stream) {
    const float* vol    = (const float*)d_in[0];
    const float* affine = (const float*)d_in[1];
    float* out = (float*)d_out;

    dim3 grid(GX * GY * GZ);   // 1-D, XCD-swizzled in-kernel
    dim3 block(256);
    SpatialTransformer_warp_kernel<<<grid, block, 0, stream>>>(vol, affine, out);
}

// Round 11
// 124.862 us; speedup vs baseline: 1.1200x; 1.0924x over previous
//
#include <hip/hip_runtime.h>

// vol [B=2, 192,192,192, C=1] fp32, affine [B,3,4] fp32,
// out [B,192,192,192,1] fp32.
#define DIM   192
#define PLANE (DIM * DIM)
#define NB    2
#define DPT   4   // d-voxels per thread (plane reuse in-thread, 16 loads/batch)
#define BH    4   // h rows per block (row reuse in L1 across waves)

typedef float f2 __attribute__((ext_vector_type(2), aligned(4)));

// (256, 2): 2 waves/EU min -> VGPR cap ~128, enough to hold the whole
// 16-load batch in registers. Without this the backend targets max
// occupancy, caps VGPRs at ~32, and SINKS the loads (observed VGPR=20-32
// in R2-R7) — killing memory-level parallelism.
__global__ __launch_bounds__(256, 2) void
SpatialTransformer_warp_kernel(const float* __restrict__ vol,
                               const float* __restrict__ affine,
                               float* __restrict__ out) {
    const int tid = threadIdx.x;
    const int w   = (blockIdx.x << 6) + (tid & 63);   // 64-lane wave along w
    const int h   = blockIdx.y * BH + (tid >> 6);     // 4 h rows per block
    const int z   = blockIdx.z;                       // (d-quad | b)
    const int b   = (z >= DIM / DPT) ? 1 : 0;
    const int d0  = (z - b * (DIM / DPT)) * DPT;

    const float* __restrict__ A = affine + b * 12;
    const float a00 = A[0], a01 = A[1], a02 = A[2],  a03 = A[3];
    const float a10 = A[4], a11 = A[5], a12 = A[6],  a13 = A[7];
    const float a20 = A[8], a21 = A[9], a22 = A[10], a23 = A[11];

    const float center = (DIM - 1) * 0.5f;   // 95.5
    const float maxl   = (float)(DIM - 1);   // 191.0
    const float maxi0  = (float)(DIM - 2);   // 190.0
    const float fplane = (float)PLANE;       // 36864.0
    const float fdim   = (float)DIM;         // 192.0

    const float ch = (float)h - center;
    const float cw = (float)w - center;

    // Partial sums independent of d
    const float pd = a01 * ch + a02 * cw + a03 + center;
    const float ph = a11 * ch + a12 * cw + a13 + center;
    const float pw = a21 * ch + a22 * cw + a23 + center;

    const float* __restrict__ vb = vol + (size_t)b * DIM * PLANE;
    float* __restrict__ ob = out + ((size_t)b * DIM + d0) * PLANE
                                 + (size_t)h * DIM + w;

    f2 r00[DPT], r01[DPT], r10[DPT], r11[DPT];
    float w0d_[DPT], w0h_[DPT], w0w_[DPT];

    // ---- batch: compute all addresses, issue all 16 loads ----
#pragma unroll
    for (int k = 0; k < DPT; ++k) {
        const float cd = (float)(d0 + k) - center;
        const float ld = a00 * cd + pd;
        const float lh = a10 * cd + ph;
        const float lw = a20 * cd + pw;

        // i0 = min(floor(clamp(l,0,191)),190); i1 = i0+1; w0 = i0+1 - clamp(l).
        // Identical to reference semantics (right-clamped corner has zero weight).
        const float td = __builtin_amdgcn_fmed3f(ld, 0.0f, maxl);
        const float th = __builtin_amdgcn_fmed3f(lh, 0.0f, maxl);
        const float tw = __builtin_amdgcn_fmed3f(lw, 0.0f, maxl);

        const float fd = fminf(floorf(td), maxi0);
        const float fh = fminf(floorf(th), maxi0);
        const float fw = fminf(floorf(tw), maxi0);

        w0d_[k] = fd + 1.0f - td;
        w0h_[k] = fh + 1.0f - th;
        w0w_[k] = fw + 1.0f - tw;

        // Flat index in float: all values integer-valued and < 2^24 -> exact.
        const int idx = (int)__builtin_fmaf(fd, fplane, __builtin_fmaf(fh, fdim, fw));
        const float* p = vb + idx;

        r00[k] = *(const f2*)(p);                   // (d0, h0, w0..w0+1)
        r01[k] = *(const f2*)(p + DIM);             // (d0, h0+1)
        r10[k] = *(const f2*)(p + PLANE);           // (d0+1, h0)
        r11[k] = *(const f2*)(p + PLANE + DIM);     // (d0+1, h0+1)
    }

    // Hard scheduling fence: nothing crosses. With the VGPR headroom from
    // __launch_bounds__(256,2) the whole 16-load batch stays in flight ->
    // one vmcnt drain for the batch instead of ~4 small serialized drains.
    __builtin_amdgcn_sched_barrier(0);

    // ---- consume ----
#pragma unroll
    for (int k = 0; k < DPT; ++k) {
        const float w0w = w0w_[k], w1w = 1.0f - w0w;
        const float w0h = w0h_[k], w1h = 1.0f - w0h;
        const float w0d = w0d_[k], w1d = 1.0f - w0d;

        const float x00 = r00[k].x * w0w + r00[k].y * w1w;
        const float x01 = r01[k].x * w0w + r01[k].y * w1w;
        const float x10 = r10[k].x * w0w + r10[k].y * w1w;
        const float x11 = r11[k].x * w0w + r11[k].y * w1w;

        const float y0 = x00 * w0h + x01 * w1h;
        const float y1 = x10 * w0h + x11 * w1h;

        __builtin_nontemporal_store(y0 * w0d + y1 * w1d, ob + k * PLANE);
    }
}

extern "C" void kernel_launch(void* const* d_in, const int* in_sizes, int n_in,
                              void* d_out, int out_size, void* d_ws, size_t ws_size,
                              hipStream_t stream) {
    const float* vol    = (const float*)d_in[0];
    const float* affine = (const float*)d_in[1];
    float* out = (float*)d_out;

    dim3 grid(DIM / 64, DIM / BH, NB * (DIM / DPT));  // (w-tile, h-tile, d-quad|b)
    dim3 block(256);
    SpatialTransformer_warp_kernel<<<grid, block, 0, stream>>>(vol, affine, out);
}